// Round 7
// baseline (120.775 us; speedup 1.0000x reference)
//
#include <hip/hip_runtime.h>
#include <math.h>

#define BB 8
#define TT 2048
#define DD 1024
#define HSZ 64

typedef __bf16 bf16_t;
typedef bf16_t bf16x8 __attribute__((ext_vector_type(8)));
typedef bf16_t bf16x4 __attribute__((ext_vector_type(4)));
typedef float f32x4 __attribute__((ext_vector_type(4)));

#define MFMA16(A, B, C) __builtin_amdgcn_mfma_f32_16x16x32_bf16(A, B, C, 0, 0, 0)

// MFMA 16x16x32 bf16 fragment conventions:
//   A-frag: lane = quad*16+l16 holds A[m=l16][k=quad*8+j]
//   B-frag: lane = quad*16+l16 holds B[k=quad*8+j][n=l16]
//   C/D   : lane holds D[m=quad*4+reg][n=l16]
// K/V frag base for (b,kt) = ((b*32+kt)*8)*512.

// ---------------------------------------------------------------------------
__global__ __launch_bounds__(256) void wt_convert(
    const float* __restrict__ Wq, const float* __restrict__ Wk,
    const float* __restrict__ Wv, bf16_t* __restrict__ Wtf)
{
    int id = blockIdx.x * 256 + threadIdx.x;      // 0 .. 196607
    int j = id & 7;
    int lane = (id >> 3) & 63;
    int chunk = (id >> 9) & 31;
    int nt = id >> 14;
    int l16 = lane & 15, quad = lane >> 4;
    int k = chunk * 32 + quad * 8 + j;
    int col = nt * 16 + l16;
    int m = col >> 6, ncol = col & 63;
    const float* W = (m == 0) ? Wq : (m == 1) ? Wk : Wv;
    float scl = (m == 0) ? 0.18033688f : 1.0f;    // 0.125 * log2(e)
    Wtf[id] = (bf16_t)(W[k * HSZ + ncol] * scl);
}

// ---------------------------------------------------------------------------
// QKV projection (r17, measured win — kept byte-identical):
//  * each wave owns FULL K=1024 for 3 output tiles nt = {w, 4+w, 8+w};
//    no cross-wave reduction, no epilogue barriers.
//  * 16 rows/block, 1024 blocks, 33 KB LDS -> 4 blocks/CU = 16 waves/CU,
//    __launch_bounds__(256,4) caps VGPR at 128.
// ---------------------------------------------------------------------------
__global__ __launch_bounds__(256, 4) void qkv_proj(
    const float* __restrict__ ctx, const bf16_t* __restrict__ Wtf,
    bf16_t* __restrict__ Q, bf16_t* __restrict__ Kf, bf16_t* __restrict__ Vf)
{
    __shared__ __align__(16) bf16_t As[16][1032];   // 33 KB

    const int tid = threadIdx.x;
    const int w = tid >> 6, lane = tid & 63;
    const int quad = lane >> 4, l16 = lane & 15;
    const size_t row0 = (size_t)blockIdx.x * 16;

    {
        const float4* csrc = (const float4*)(ctx + row0 * DD);
        #pragma unroll
        for (int i = 0; i < 16; ++i) {
            float4 v = csrc[i * 256 + tid];
            bf16x4 bv;
            bv[0] = (bf16_t)v.x; bv[1] = (bf16_t)v.y;
            bv[2] = (bf16_t)v.z; bv[3] = (bf16_t)v.w;
            *(bf16x4*)&As[i][tid * 4] = bv;
        }
    }
    __syncthreads();

    f32x4 aq = (f32x4){0.f, 0.f, 0.f, 0.f};
    f32x4 ak = (f32x4){0.f, 0.f, 0.f, 0.f};
    f32x4 av = (f32x4){0.f, 0.f, 0.f, 0.f};

    const bf16_t* wbase = Wtf + lane * 8;
    const bf16_t* wq = wbase + (size_t)(w)     * 32 * 512;
    const bf16_t* wk = wbase + (size_t)(4 + w) * 32 * 512;
    const bf16_t* wv = wbase + (size_t)(8 + w) * 32 * 512;

    #pragma unroll 4
    for (int chunk = 0; chunk < 32; ++chunk) {
        bf16x8 af = *(const bf16x8*)&As[l16][chunk * 32 + quad * 8];
        bf16x8 bq = *(const bf16x8*)(wq + (size_t)chunk * 512);
        bf16x8 bk = *(const bf16x8*)(wk + (size_t)chunk * 512);
        bf16x8 bv = *(const bf16x8*)(wv + (size_t)chunk * 512);
        aq = MFMA16(af, bq, aq);
        ak = MFMA16(af, bk, ak);
        av = MFMA16(af, bv, av);
    }

    // ---- direct per-wave epilogue (no cross-wave reduction) ----
    const int bb   = (int)(row0 >> 11);
    const int tloc = (int)(row0 & 2047);
    const int kt   = tloc >> 6;

    {   // Q: col-tile w, row-major
        const int col = w * 16 + l16;
        #pragma unroll
        for (int reg = 0; reg < 4; ++reg)
            Q[(row0 + quad * 4 + reg) * HSZ + col] = (bf16_t)aq[reg];
    }
    {   // K -> frag order (kt, n=nn, ks); d-group = w
        const int nn = (tloc >> 4) & 3;
        const int ks = w >> 1;
        const int quadf = (w & 1) * 2 + (l16 >> 3);
        const int jj = l16 & 7;
        const size_t fb = ((((size_t)bb * 32 + kt) * 4 + nn) * 2 + ks) * 512;
        #pragma unroll
        for (int reg = 0; reg < 4; ++reg)
            Kf[fb + (quadf * 16 + quad * 4 + reg) * 8 + jj] = (bf16_t)ak[reg];
    }
    {   // V -> frag order (kt, ks, dt=w)
        const int t0 = tloc + quad * 4;
        const int ks = (t0 >> 5) & 1;
        const int quadf = (t0 >> 3) & 3;
        const int j0 = t0 & 7;
        const size_t fb = ((((size_t)bb * 32 + kt) * 2 + ks) * 4 + w) * 512;
        bf16x4 v;
        #pragma unroll
        for (int reg = 0; reg < 4; ++reg) v[reg] = (bf16_t)av[reg];
        *(bf16x4*)(Vf + fb + (quadf * 16 + l16) * 8 + j0) = v;
    }
}

// ---------------------------------------------------------------------------
// Fused flash attention r18: r13 structure, but ILP -> TLP trade:
//  * kA/kB double buffer DROPPED (-32 VGPR): kf loaded at the top of each
//    owned iteration.  r14/r15 proved deeper in-register pipelining loses;
//    this goes the other way: cut VGPR under 170 so 3 waves/SIMD fit.
//  * __launch_bounds__(256, 3): 12 waves/CU (was 8) -> +50% TLP to cover
//    the serial K-load -> S-MFMA -> exp2 -> LDS-P -> PV chain.
// Everything else (32-query strips, balanced pairing, unioned LDS, causal
// tail handling, cross-wave reduction) identical to r13.
// ---------------------------------------------------------------------------
__device__ __forceinline__ void load_kfrags(
    const bf16_t* __restrict__ Kf, size_t bofs, int kt, int lane, bf16x8* kf)
{
    const bf16_t* kbase = Kf + ((bofs + (size_t)kt) * 8) * 512 + lane * 8;
    #pragma unroll
    for (int i = 0; i < 8; ++i)
        kf[i] = *(const bf16x8*)(kbase + i * 512);
}

#define WREG 8704                       // per-wave union region bytes

__global__ __launch_bounds__(256, 3) void attn_kernel(
    const bf16_t* __restrict__ Q, const bf16_t* __restrict__ Kf,
    const bf16_t* __restrict__ Vf, float* __restrict__ O)
{
    // per-wave union: Ps [32][72] bf16 (4608 B)  |  Ored [32][68] f32 (8704 B)
    __shared__ __align__(16) char sm[4 * WREG + 512];

    const int tid = threadIdx.x;
    const int w = tid >> 6, lane = tid & 63;
    const int quad = lane >> 4, l16 = lane & 15;

    bf16_t (*Psw)[72] = (bf16_t (*)[72])(sm + w * WREG);
    float  (*Orw)[68] = (float  (*)[68])(sm + w * WREG);
    float* Lred = (float*)(sm + 4 * WREG);          // [4][32]

    const int z = blockIdx.x;
    const int b = z & 7;                 // batch -> XCD pinning
    const int s = z >> 3;                // 0..63
    const int js = (s < 32) ? (63 - s) : (s - 32);   // balanced pairing
    const size_t base = (size_t)b * TT * HSZ;
    const size_t bofs = (size_t)b * 32;  // tile units
    const int ntile = (js >> 1) + 1;
    const int q0 = js << 5;              // first query of strip

    // Q as B-operand (Q^T), two 16-query groups
    bf16x8 qf0[2], qf1[2];
    #pragma unroll
    for (int g = 0; g < 2; ++g) {
        const bf16_t* qp = Q + base + (size_t)(q0 + g * 16 + l16) * HSZ + quad * 8;
        qf0[g] = *(const bf16x8*)qp;
        qf1[g] = *(const bf16x8*)(qp + 32);
    }

    bf16x8 onesA;                        // all-ones A-frag for the row-sum
    #pragma unroll
    for (int i = 0; i < 8; ++i) onesA[i] = (bf16_t)1.0f;

    f32x4 o[2][4];
    f32x4 lacc[2];
    #pragma unroll
    for (int g = 0; g < 2; ++g) {
        #pragma unroll
        for (int dt = 0; dt < 4; ++dt) o[g][dt] = (f32x4){0.f, 0.f, 0.f, 0.f};
        lacc[g] = (f32x4){0.f, 0.f, 0.f, 0.f};
    }

    bf16x8 kf[8];

    auto process = [&](int kt) {
        const bool last = (kt == ntile - 1);

        const bf16_t* vbase = Vf + ((bofs + (size_t)kt) * 8) * 512 + lane * 8;
        bf16x8 vf[8];
        #pragma unroll
        for (int i = 0; i < 8; ++i)
            vf[i] = *(const bf16x8*)(vbase + i * 512);   // ks0: dt 0..3, ks1: 4..7

        #pragma unroll
        for (int g = 0; g < 2; ++g) {
            const int jmg = (2 * js + g) & 3;
            const int nv = last ? jmg + 1 : 4;

            // ---- S^T = K Q^T (subtile n: keys n*16..+15 x 16 queries) ----
            f32x4 sc[4];
            #pragma unroll
            for (int n = 0; n < 4; ++n) {
                if (n < nv) {
                    f32x4 a = (f32x4){0.f, 0.f, 0.f, 0.f};
                    a = MFMA16(kf[2 * n], qf0[g], a);
                    a = MFMA16(kf[2 * n + 1], qf1[g], a);
                    sc[n] = a;
                }
            }

            // ---- p = exp2(s); transposed causal mask: key > query ----
            if (last) {
                #pragma unroll
                for (int n = 0; n < 4; ++n) {
                    if (n < nv) {
                        #pragma unroll
                        for (int reg = 0; reg < 4; ++reg) {
                            bool masked = (n == jmg) && (quad * 4 + reg > l16);
                            float p = __builtin_amdgcn_exp2f(sc[n][reg]);
                            sc[n][reg] = masked ? 0.f : p;
                        }
                    }
                }
            } else {
                #pragma unroll
                for (int n = 0; n < 4; ++n)
                    #pragma unroll
                    for (int reg = 0; reg < 4; ++reg)
                        sc[n][reg] = __builtin_amdgcn_exp2f(sc[n][reg]);
            }

            // ---- P -> LDS: lane writes 4 consecutive keys (one b64) per n ----
            #pragma unroll
            for (int n = 0; n < 4; ++n) {
                bf16x4 pv;
                #pragma unroll
                for (int reg = 0; reg < 4; ++reg)
                    pv[reg] = (bf16_t)((n < nv) ? sc[n][reg] : 0.f);
                *(bf16x4*)&Psw[g * 16 + l16][n * 16 + quad * 4] = pv;
            }
        }

        // ---- O^T += Vt P^T ;  l += 1 P^T  (per query group) ----
        #pragma unroll
        for (int g = 0; g < 2; ++g) {
            const int nv = last ? ((2 * js + g) & 3) + 1 : 4;
            const int ksm = (nv > 2) ? 2 : 1;
            bf16x8 pf0 = *(const bf16x8*)&Psw[g * 16 + l16][quad * 8];
            bf16x8 pf1 = *(const bf16x8*)&Psw[g * 16 + l16][32 + quad * 8];
            #pragma unroll
            for (int dt = 0; dt < 4; ++dt) {
                o[g][dt] = MFMA16(vf[dt], pf0, o[g][dt]);
                if (ksm == 2) o[g][dt] = MFMA16(vf[4 + dt], pf1, o[g][dt]);
            }
            lacc[g] = MFMA16(onesA, pf0, lacc[g]);
            if (ksm == 2) lacc[g] = MFMA16(onesA, pf1, lacc[g]);
        }
    };

    // wave w owns kt = w, w+4, ...; TLP (12 waves/CU) hides the load chain.
    if (w < ntile) {
        for (int kt = w; kt < ntile; kt += 4) {
            load_kfrags(Kf, bofs, kt, lane, kf);
            process(kt);
        }
    }

    // ---- per-wave O^T / l partials to LDS (Ps region now dead) ----
    #pragma unroll
    for (int g = 0; g < 2; ++g) {
        #pragma unroll
        for (int dt = 0; dt < 4; ++dt)
            *(f32x4*)&Orw[g * 16 + l16][dt * 16 + quad * 4] = o[g][dt];
        if (quad == 0) Lred[w * 32 + g * 16 + l16] = lacc[g][0];
    }
    __syncthreads();

    // ---- cross-wave reduction: O = (sum O^T) / (sum l) ----
    #pragma unroll
    for (int rep = 0; rep < 2; ++rep) {
        const int idx = rep * 256 + tid;
        const int query = idx >> 4, d4 = idx & 15;
        float l = Lred[0 * 32 + query] + Lred[1 * 32 + query] +
                  Lred[2 * 32 + query] + Lred[3 * 32 + query];
        f32x4 sv = *(const f32x4*)((const float*)(sm + 0 * WREG) + query * 68 + d4 * 4);
        sv += *(const f32x4*)((const float*)(sm + 1 * WREG) + query * 68 + d4 * 4);
        sv += *(const f32x4*)((const float*)(sm + 2 * WREG) + query * 68 + d4 * 4);
        sv += *(const f32x4*)((const float*)(sm + 3 * WREG) + query * 68 + d4 * 4);
        const float linv = 1.f / l;
        float4 outv = make_float4(sv[0] * linv, sv[1] * linv,
                                  sv[2] * linv, sv[3] * linv);
        *(float4*)(O + base + (size_t)(q0 + query) * HSZ + d4 * 4) = outv;
    }
}

// ---------------------------------------------------------------------------
extern "C" void kernel_launch(void* const* d_in, const int* in_sizes, int n_in,
                              void* d_out, int out_size, void* d_ws, size_t ws_size,
                              hipStream_t stream) {
    const float* ctx = (const float*)d_in[0];
    const float* Wq  = (const float*)d_in[1];
    const float* Wk  = (const float*)d_in[2];
    const float* Wv  = (const float*)d_in[3];
    float* out = (float*)d_out;

    const size_t NQ = (size_t)BB * TT * HSZ;       // 1,048,576
    bf16_t* Qw  = (bf16_t*)d_ws;
    bf16_t* Kfw = Qw + NQ;                         // frag-ordered
    bf16_t* Vfw = Kfw + NQ;                        // frag-ordered
    bf16_t* Wtf = Vfw + NQ;                        // frag-ordered weights

    wt_convert<<<768, 256, 0, stream>>>(Wq, Wk, Wv, Wtf);
    qkv_proj<<<1024, 256, 0, stream>>>(ctx, Wtf, Qw, Kfw, Vfw);
    attn_kernel<<<512, 256, 0, stream>>>(Qw, Kfw, Vfw, out);
}

// Round 8
// 119.934 us; speedup vs baseline: 1.0070x; 1.0070x over previous
//
#include <hip/hip_runtime.h>
#include <math.h>

#define BB 8
#define TT 2048
#define DD 1024
#define HSZ 64

typedef __bf16 bf16_t;
typedef bf16_t bf16x8 __attribute__((ext_vector_type(8)));
typedef bf16_t bf16x4 __attribute__((ext_vector_type(4)));
typedef float f32x4 __attribute__((ext_vector_type(4)));

#define MFMA16(A, B, C) __builtin_amdgcn_mfma_f32_16x16x32_bf16(A, B, C, 0, 0, 0)

// MFMA 16x16x32 bf16 fragment conventions:
//   A-frag: lane = quad*16+l16 holds A[m=l16][k=quad*8+j]
//   B-frag: lane = quad*16+l16 holds B[k=quad*8+j][n=l16]
//   C/D   : lane holds D[m=quad*4+reg][n=l16]
// K/V frag base for (b,kt) = ((b*32+kt)*8)*512.

// ---------------------------------------------------------------------------
__global__ __launch_bounds__(256) void wt_convert(
    const float* __restrict__ Wq, const float* __restrict__ Wk,
    const float* __restrict__ Wv, bf16_t* __restrict__ Wtf)
{
    int id = blockIdx.x * 256 + threadIdx.x;      // 0 .. 196607
    int j = id & 7;
    int lane = (id >> 3) & 63;
    int chunk = (id >> 9) & 31;
    int nt = id >> 14;
    int l16 = lane & 15, quad = lane >> 4;
    int k = chunk * 32 + quad * 8 + j;
    int col = nt * 16 + l16;
    int m = col >> 6, ncol = col & 63;
    const float* W = (m == 0) ? Wq : (m == 1) ? Wk : Wv;
    float scl = (m == 0) ? 0.18033688f : 1.0f;    // 0.125 * log2(e)
    Wtf[id] = (bf16_t)(W[k * HSZ + ncol] * scl);
}

// ---------------------------------------------------------------------------
// QKV projection (r17, measured win — kept byte-identical):
//  * each wave owns FULL K=1024 for 3 output tiles nt = {w, 4+w, 8+w};
//    no cross-wave reduction, no epilogue barriers.
//  * 16 rows/block, 1024 blocks, 33 KB LDS -> 4 blocks/CU = 16 waves/CU,
//    __launch_bounds__(256,4) caps VGPR at 128.
// ---------------------------------------------------------------------------
__global__ __launch_bounds__(256, 4) void qkv_proj(
    const float* __restrict__ ctx, const bf16_t* __restrict__ Wtf,
    bf16_t* __restrict__ Q, bf16_t* __restrict__ Kf, bf16_t* __restrict__ Vf)
{
    __shared__ __align__(16) bf16_t As[16][1032];   // 33 KB

    const int tid = threadIdx.x;
    const int w = tid >> 6, lane = tid & 63;
    const int quad = lane >> 4, l16 = lane & 15;
    const size_t row0 = (size_t)blockIdx.x * 16;

    {
        const float4* csrc = (const float4*)(ctx + row0 * DD);
        #pragma unroll
        for (int i = 0; i < 16; ++i) {
            float4 v = csrc[i * 256 + tid];
            bf16x4 bv;
            bv[0] = (bf16_t)v.x; bv[1] = (bf16_t)v.y;
            bv[2] = (bf16_t)v.z; bv[3] = (bf16_t)v.w;
            *(bf16x4*)&As[i][tid * 4] = bv;
        }
    }
    __syncthreads();

    f32x4 aq = (f32x4){0.f, 0.f, 0.f, 0.f};
    f32x4 ak = (f32x4){0.f, 0.f, 0.f, 0.f};
    f32x4 av = (f32x4){0.f, 0.f, 0.f, 0.f};

    const bf16_t* wbase = Wtf + lane * 8;
    const bf16_t* wq = wbase + (size_t)(w)     * 32 * 512;
    const bf16_t* wk = wbase + (size_t)(4 + w) * 32 * 512;
    const bf16_t* wv = wbase + (size_t)(8 + w) * 32 * 512;

    #pragma unroll 4
    for (int chunk = 0; chunk < 32; ++chunk) {
        bf16x8 af = *(const bf16x8*)&As[l16][chunk * 32 + quad * 8];
        bf16x8 bq = *(const bf16x8*)(wq + (size_t)chunk * 512);
        bf16x8 bk = *(const bf16x8*)(wk + (size_t)chunk * 512);
        bf16x8 bv = *(const bf16x8*)(wv + (size_t)chunk * 512);
        aq = MFMA16(af, bq, aq);
        ak = MFMA16(af, bk, ak);
        av = MFMA16(af, bv, av);
    }

    // ---- direct per-wave epilogue (no cross-wave reduction) ----
    const int bb   = (int)(row0 >> 11);
    const int tloc = (int)(row0 & 2047);
    const int kt   = tloc >> 6;

    {   // Q: col-tile w, row-major
        const int col = w * 16 + l16;
        #pragma unroll
        for (int reg = 0; reg < 4; ++reg)
            Q[(row0 + quad * 4 + reg) * HSZ + col] = (bf16_t)aq[reg];
    }
    {   // K -> frag order (kt, n=nn, ks); d-group = w
        const int nn = (tloc >> 4) & 3;
        const int ks = w >> 1;
        const int quadf = (w & 1) * 2 + (l16 >> 3);
        const int jj = l16 & 7;
        const size_t fb = ((((size_t)bb * 32 + kt) * 4 + nn) * 2 + ks) * 512;
        #pragma unroll
        for (int reg = 0; reg < 4; ++reg)
            Kf[fb + (quadf * 16 + quad * 4 + reg) * 8 + jj] = (bf16_t)ak[reg];
    }
    {   // V -> frag order (kt, ks, dt=w)
        const int t0 = tloc + quad * 4;
        const int ks = (t0 >> 5) & 1;
        const int quadf = (t0 >> 3) & 3;
        const int j0 = t0 & 7;
        const size_t fb = ((((size_t)bb * 32 + kt) * 2 + ks) * 4 + w) * 512;
        bf16x4 v;
        #pragma unroll
        for (int reg = 0; reg < 4; ++reg) v[reg] = (bf16_t)av[reg];
        *(bf16x4*)(Vf + fb + (quadf * 16 + l16) * 8 + j0) = v;
    }
}

// ---------------------------------------------------------------------------
// Fused flash attention r19 = r13 structure (measured best) + T5 setprio
// around the two MFMA clusters ONLY (single-variable A/B vs r17's 120.24).
// Mechanism fit: waves here are independent (no intra-loop barriers) and sit
// at different kt phases -> m191's positive regime, not m190's lockstep null.
// VGPR-neutral, correctness-neutral.
// ---------------------------------------------------------------------------
__device__ __forceinline__ void load_kfrags(
    const bf16_t* __restrict__ Kf, size_t bofs, int kt, int lane, bf16x8* kf)
{
    const bf16_t* kbase = Kf + ((bofs + (size_t)kt) * 8) * 512 + lane * 8;
    #pragma unroll
    for (int i = 0; i < 8; ++i)
        kf[i] = *(const bf16x8*)(kbase + i * 512);
}

#define WREG 8704                       // per-wave union region bytes

__global__ __launch_bounds__(256, 2) void attn_kernel(
    const bf16_t* __restrict__ Q, const bf16_t* __restrict__ Kf,
    const bf16_t* __restrict__ Vf, float* __restrict__ O)
{
    // per-wave union: Ps [32][72] bf16 (4608 B)  |  Ored [32][68] f32 (8704 B)
    __shared__ __align__(16) char sm[4 * WREG + 512];

    const int tid = threadIdx.x;
    const int w = tid >> 6, lane = tid & 63;
    const int quad = lane >> 4, l16 = lane & 15;

    bf16_t (*Psw)[72] = (bf16_t (*)[72])(sm + w * WREG);
    float  (*Orw)[68] = (float  (*)[68])(sm + w * WREG);
    float* Lred = (float*)(sm + 4 * WREG);          // [4][32]

    const int z = blockIdx.x;
    const int b = z & 7;                 // batch -> XCD pinning
    const int s = z >> 3;                // 0..63
    const int js = (s < 32) ? (63 - s) : (s - 32);   // balanced pairing
    const size_t base = (size_t)b * TT * HSZ;
    const size_t bofs = (size_t)b * 32;  // tile units
    const int ntile = (js >> 1) + 1;
    const int q0 = js << 5;              // first query of strip

    // Q as B-operand (Q^T), two 16-query groups
    bf16x8 qf0[2], qf1[2];
    #pragma unroll
    for (int g = 0; g < 2; ++g) {
        const bf16_t* qp = Q + base + (size_t)(q0 + g * 16 + l16) * HSZ + quad * 8;
        qf0[g] = *(const bf16x8*)qp;
        qf1[g] = *(const bf16x8*)(qp + 32);
    }

    bf16x8 onesA;                        // all-ones A-frag for the row-sum
    #pragma unroll
    for (int i = 0; i < 8; ++i) onesA[i] = (bf16_t)1.0f;

    f32x4 o[2][4];
    f32x4 lacc[2];
    #pragma unroll
    for (int g = 0; g < 2; ++g) {
        #pragma unroll
        for (int dt = 0; dt < 4; ++dt) o[g][dt] = (f32x4){0.f, 0.f, 0.f, 0.f};
        lacc[g] = (f32x4){0.f, 0.f, 0.f, 0.f};
    }

    bf16x8 kA[8], kB[8];

    auto process = [&](int kt, const bf16x8* kf) {
        const bool last = (kt == ntile - 1);

        const bf16_t* vbase = Vf + ((bofs + (size_t)kt) * 8) * 512 + lane * 8;
        bf16x8 vf[8];
        #pragma unroll
        for (int i = 0; i < 8; ++i)
            vf[i] = *(const bf16x8*)(vbase + i * 512);   // ks0: dt 0..3, ks1: 4..7

        #pragma unroll
        for (int g = 0; g < 2; ++g) {
            const int jmg = (2 * js + g) & 3;
            const int nv = last ? jmg + 1 : 4;

            // ---- S^T = K Q^T (subtile n: keys n*16..+15 x 16 queries) ----
            f32x4 sc[4];
            __builtin_amdgcn_s_setprio(1);
            #pragma unroll
            for (int n = 0; n < 4; ++n) {
                if (n < nv) {
                    f32x4 a = (f32x4){0.f, 0.f, 0.f, 0.f};
                    a = MFMA16(kf[2 * n], qf0[g], a);
                    a = MFMA16(kf[2 * n + 1], qf1[g], a);
                    sc[n] = a;
                }
            }
            __builtin_amdgcn_s_setprio(0);

            // ---- p = exp2(s); transposed causal mask: key > query ----
            if (last) {
                #pragma unroll
                for (int n = 0; n < 4; ++n) {
                    if (n < nv) {
                        #pragma unroll
                        for (int reg = 0; reg < 4; ++reg) {
                            bool masked = (n == jmg) && (quad * 4 + reg > l16);
                            float p = __builtin_amdgcn_exp2f(sc[n][reg]);
                            sc[n][reg] = masked ? 0.f : p;
                        }
                    }
                }
            } else {
                #pragma unroll
                for (int n = 0; n < 4; ++n)
                    #pragma unroll
                    for (int reg = 0; reg < 4; ++reg)
                        sc[n][reg] = __builtin_amdgcn_exp2f(sc[n][reg]);
            }

            // ---- P -> LDS: lane writes 4 consecutive keys (one b64) per n ----
            #pragma unroll
            for (int n = 0; n < 4; ++n) {
                bf16x4 pv;
                #pragma unroll
                for (int reg = 0; reg < 4; ++reg)
                    pv[reg] = (bf16_t)((n < nv) ? sc[n][reg] : 0.f);
                *(bf16x4*)&Psw[g * 16 + l16][n * 16 + quad * 4] = pv;
            }
        }

        // ---- O^T += Vt P^T ;  l += 1 P^T  (per query group) ----
        #pragma unroll
        for (int g = 0; g < 2; ++g) {
            const int nv = last ? ((2 * js + g) & 3) + 1 : 4;
            const int ksm = (nv > 2) ? 2 : 1;
            bf16x8 pf0 = *(const bf16x8*)&Psw[g * 16 + l16][quad * 8];
            bf16x8 pf1 = *(const bf16x8*)&Psw[g * 16 + l16][32 + quad * 8];
            __builtin_amdgcn_s_setprio(1);
            #pragma unroll
            for (int dt = 0; dt < 4; ++dt) {
                o[g][dt] = MFMA16(vf[dt], pf0, o[g][dt]);
                if (ksm == 2) o[g][dt] = MFMA16(vf[4 + dt], pf1, o[g][dt]);
            }
            lacc[g] = MFMA16(onesA, pf0, lacc[g]);
            if (ksm == 2) lacc[g] = MFMA16(onesA, pf1, lacc[g]);
            __builtin_amdgcn_s_setprio(0);
        }
    };

    // software-pipelined: wave w owns kt = w, w+4, ...; load(t+4) before
    // process(t).  Inactive waves (w >= ntile) still reach the barrier.
    if (w < ntile) {
        load_kfrags(Kf, bofs, w, lane, kA);
        for (int kt = w; kt < ntile; kt += 8) {
            if (kt + 4 < ntile) load_kfrags(Kf, bofs, kt + 4, lane, kB);
            process(kt, kA);
            if (kt + 4 < ntile) {
                if (kt + 8 < ntile) load_kfrags(Kf, bofs, kt + 8, lane, kA);
                process(kt + 4, kB);
            }
        }
    }

    // ---- per-wave O^T / l partials to LDS (Ps region now dead) ----
    #pragma unroll
    for (int g = 0; g < 2; ++g) {
        #pragma unroll
        for (int dt = 0; dt < 4; ++dt)
            *(f32x4*)&Orw[g * 16 + l16][dt * 16 + quad * 4] = o[g][dt];
        if (quad == 0) Lred[w * 32 + g * 16 + l16] = lacc[g][0];
    }
    __syncthreads();

    // ---- cross-wave reduction: O = (sum O^T) / (sum l) ----
    #pragma unroll
    for (int rep = 0; rep < 2; ++rep) {
        const int idx = rep * 256 + tid;
        const int query = idx >> 4, d4 = idx & 15;
        float l = Lred[0 * 32 + query] + Lred[1 * 32 + query] +
                  Lred[2 * 32 + query] + Lred[3 * 32 + query];
        f32x4 sv = *(const f32x4*)((const float*)(sm + 0 * WREG) + query * 68 + d4 * 4);
        sv += *(const f32x4*)((const float*)(sm + 1 * WREG) + query * 68 + d4 * 4);
        sv += *(const f32x4*)((const float*)(sm + 2 * WREG) + query * 68 + d4 * 4);
        sv += *(const f32x4*)((const float*)(sm + 3 * WREG) + query * 68 + d4 * 4);
        const float linv = 1.f / l;
        float4 outv = make_float4(sv[0] * linv, sv[1] * linv,
                                  sv[2] * linv, sv[3] * linv);
        *(float4*)(O + base + (size_t)(q0 + query) * HSZ + d4 * 4) = outv;
    }
}

// ---------------------------------------------------------------------------
extern "C" void kernel_launch(void* const* d_in, const int* in_sizes, int n_in,
                              void* d_out, int out_size, void* d_ws, size_t ws_size,
                              hipStream_t stream) {
    const float* ctx = (const float*)d_in[0];
    const float* Wq  = (const float*)d_in[1];
    const float* Wk  = (const float*)d_in[2];
    const float* Wv  = (const float*)d_in[3];
    float* out = (float*)d_out;

    const size_t NQ = (size_t)BB * TT * HSZ;       // 1,048,576
    bf16_t* Qw  = (bf16_t*)d_ws;
    bf16_t* Kfw = Qw + NQ;                         // frag-ordered
    bf16_t* Vfw = Kfw + NQ;                        // frag-ordered
    bf16_t* Wtf = Vfw + NQ;                        // frag-ordered weights

    wt_convert<<<768, 256, 0, stream>>>(Wq, Wk, Wv, Wtf);
    qkv_proj<<<1024, 256, 0, stream>>>(ctx, Wtf, Qw, Kfw, Vfw);
    attn_kernel<<<512, 256, 0, stream>>>(Qw, Kfw, Vfw, out);
}